// Round 8
// baseline (3219.642 us; speedup 1.0000x reference)
//
#include <hip/hip_runtime.h>
#include <hip/hip_bf16.h>

typedef __hip_bfloat16 bf16;
typedef __attribute__((ext_vector_type(4))) float floatx4;
typedef __attribute__((ext_vector_type(8))) short shortx8;

#define MFMA16(a, b, c) __builtin_amdgcn_mfma_f32_16x16x32_bf16(a, b, c, 0, 0, 0)

__device__ __forceinline__ void gll16(const bf16* g, void* l) {
  __builtin_amdgcn_global_load_lds((const __attribute__((address_space(1))) unsigned int*)g,
                                   (__attribute__((address_space(3))) unsigned int*)l,
                                   16, 0, 0);
}

__device__ __forceinline__ float b2f(short s) {
  return __bfloat162float(__builtin_bit_cast(bf16, (unsigned short)s));
}
__device__ __forceinline__ short f2b(float f) {
  return __builtin_bit_cast(short, __float2bfloat16(f));
}

// ---------------------------------------------------------------------------
// fused fp32 -> bf16 converts: src (16384 blks) + 6 weights (8192 blks)
// ---------------------------------------------------------------------------
__global__ __launch_bounds__(256) void f2b_all(
    const float* __restrict__ src, const float* __restrict__ Wq,
    const float* __restrict__ Wk, const float* __restrict__ Wv,
    const float* __restrict__ Wo, const float* __restrict__ W1,
    const float* __restrict__ W2, bf16* __restrict__ src_bf,
    bf16* __restrict__ Wq_b, bf16* __restrict__ Wk_b, bf16* __restrict__ Wv_b,
    bf16* __restrict__ Wo_b, bf16* __restrict__ W1_b, bf16* __restrict__ W2_b) {
  const int blk = blockIdx.x;
  const float* in;
  bf16* out;
  int off;
  if (blk < 16384)      { in = src; out = src_bf; off = blk; }
  else if (blk < 17408) { in = Wq; out = Wq_b; off = blk - 16384; }
  else if (blk < 18432) { in = Wk; out = Wk_b; off = blk - 17408; }
  else if (blk < 19456) { in = Wv; out = Wv_b; off = blk - 18432; }
  else if (blk < 20480) { in = Wo; out = Wo_b; off = blk - 19456; }
  else if (blk < 22528) { in = W1; out = W1_b; off = blk - 20480; }
  else                  { in = W2; out = W2_b; off = blk - 22528; }
  const int i = (off * 256 + threadIdx.x) * 4;
  float4 v = *(const float4*)(in + i);
  ushort4 u;
  u.x = (unsigned short)f2b(v.x);
  u.y = (unsigned short)f2b(v.y);
  u.z = (unsigned short)f2b(v.z);
  u.w = (unsigned short)f2b(v.w);
  *(ushort4*)(out + i) = u;
}

// ---------------------------------------------------------------------------
// NT GEMM, 256x256 tile, BK=32, 512 threads (8 waves 2Mx4N, wave tile
// 128x64, acc[8][4]=128 VGPR), 2-deep LDS ring of 32 KiB = 64 KiB/block,
// __launch_bounds__(512,4) -> 2 blocks/CU (16 waves).
//
// ROUND-7 LESSON: 2 blocks/CU via a SMALLER TILE regressed (1.5x total
// staged bytes). This keeps the 256^2 tile's traffic profile and gets the
// second block by halving ring depth only. ROUND-6 PROBE: one 8-wave
// barriered block caps at ~60% of the MFMA floor even with zero memory
// traffic; m114 measured that a co-resident block overlaps MFMA/VALU/drain
// windows automatically. So the loop is the SIMPLE m97-family form -- plain
// compiler-scheduled LDS reads (fine lgkmcnt), stage(t+1) after the reads,
// one __syncthreads per tile (full drain BY DESIGN; the other block covers
// it). No inline-asm gates, no setprio (m190).
//
// EPI: 1 id->bf16 ; 2 relu->bf16 ; 3 +res(fp32)->bf16 ; 4 fused QKV
//      (block-uniform sel: phi->phiQ/phiK, id->V) ; 5 +res(bf16)->bf16
// ---------------------------------------------------------------------------
template <int EPI>
__global__ __launch_bounds__(512, 4) void gemm256(
    const bf16* __restrict__ A, const bf16* __restrict__ Bw,
    const float* __restrict__ bias0, const float* __restrict__ bias1,
    const float* __restrict__ bias2, const float* __restrict__ resf,
    const bf16* __restrict__ resb, void* __restrict__ out0,
    void* __restrict__ out1, void* __restrict__ out2, const int M,
    const int K) {
  // slot s (s=kt&1) at s*32768: A rows0-127 @0, rows128-255 @8192,
  //                             B cols0-127 @16384, cols128-255 @24576
  __shared__ __align__(16) char smem[65536];
  const int tid = threadIdx.x;
  const int lane = tid & 63, wave = tid >> 6;
  const int wm = wave & 1, wn = wave >> 1;
  const int bm = blockIdx.x, bn = blockIdx.y;
  const int NK = K >> 5;

  // staging: thread -> (row = tid>>2 in a 128-row half, 16-B chunk = tid&3),
  // source chunk pre-swizzled so linear global_load_lds dest yields the
  // swizzled layout (rule 21).
  const int srow = tid >> 2;
  const int schunk = (tid & 3) ^ ((srow >> 1) & 3);
  const bf16* gA0 = A + (size_t)(bm * 256 + srow) * K + schunk * 8;
  const bf16* gA1 = gA0 + (size_t)128 * K;
  const bf16* gB0 = Bw + (size_t)(bn * 256 + srow) * K + schunk * 8;
  const bf16* gB1 = gB0 + (size_t)128 * K;
  const unsigned ldst = (unsigned)wave * 1024u;  // wave-uniform

  // fragment-read offsets (swizzled chunk on read side)
  const int frow = lane & 15;
  const unsigned fch16 = (unsigned)(((lane >> 4) ^ ((frow >> 1) & 3))) << 4;
  const unsigned aoff0 = (unsigned)(wm * 8192 + frow * 64) + fch16;
  const unsigned boff0 = 16384u + (unsigned)(wn * 4096 + frow * 64) + fch16;

  floatx4 acc[8][4] = {};

#define STAGE(t)                                                         \
  {                                                                      \
    const int kk = (t) * 32;                                             \
    const unsigned so = (unsigned)(((t) & 1) * 32768);                   \
    gll16(gA0 + kk, smem + so + ldst);                                   \
    gll16(gA1 + kk, smem + so + 8192 + ldst);                            \
    gll16(gB0 + kk, smem + so + 16384 + ldst);                           \
    gll16(gB1 + kk, smem + so + 24576 + ldst);                           \
  }

  STAGE(0);
  __syncthreads();  // drains stage(0)

  for (int kt = 0; kt < NK; ++kt) {
    const unsigned so = (unsigned)((kt & 1) * 32768);
    shortx8 bfr[4], af[8];
#pragma unroll
    for (int j = 0; j < 4; j++)
      bfr[j] = *(const shortx8*)(smem + so + boff0 + j * 1024);
#pragma unroll
    for (int i = 0; i < 8; i++)
      af[i] = *(const shortx8*)(smem + so + aoff0 + i * 1024);
    if (kt + 1 < NK) STAGE(kt + 1);  // other slot; no hazard with reads
#pragma unroll
    for (int i = 0; i < 8; i++)
#pragma unroll
      for (int j = 0; j < 4; j++) acc[i][j] = MFMA16(af[i], bfr[j], acc[i][j]);
    __syncthreads();  // drains vmcnt: stage(kt+1) resident for next iter
  }
#undef STAGE

  // ---- epilogue: fragments -> LDS -> coalesced 16-B row-linear stores ----
  // stride 268 shorts (536 B): measured 0 bank conflicts.
  bf16* cep = (bf16*)smem;  // [32][268] = 17152 B
  const float* bptr = bias0;
  bf16* ob = (bf16*)out0;
  int colbase = bn * 256;
  int phi = 0;
  if (EPI == 4) {
    const int sel = bn >> 2;
    bptr = (sel == 0) ? bias0 : (sel == 1) ? bias1 : bias2;
    ob = (bf16*)((sel == 0) ? out0 : (sel == 1) ? out1 : out2);
    colbase = (bn & 3) * 256;
    phi = (sel < 2);
  }
  const int e = lane & 15, q4 = (lane >> 4) << 2;
  float bj[4];
#pragma unroll
  for (int j = 0; j < 4; j++) bj[j] = bptr[colbase + wn * 64 + j * 16 + e];

  const int ridx = tid >> 4;      // 0..31
  const int cc = (tid & 15) * 8;  // 0..120
  const int grow_base = bm * 256 + (ridx >> 4) * 128 + (ridx & 15);

#pragma unroll
  for (int i3 = 0; i3 < 8; i3++) {
    __syncthreads();
#pragma unroll
    for (int j = 0; j < 4; j++)
#pragma unroll
      for (int r = 0; r < 4; r++) {
        float v = acc[i3][j][r] + bj[j];
        if (EPI == 4 && phi) v = v > 0.f ? v + 1.f : __expf(v);
        if (EPI == 2) v = fmaxf(v, 0.f);
        cep[(wm * 16 + q4 + r) * 268 + wn * 64 + j * 16 + e] =
            __builtin_bit_cast(bf16, f2b(v));
      }
    __syncthreads();
    const int grow = grow_base + i3 * 16;
#pragma unroll
    for (int h = 0; h < 2; h++) {
      const int col = cc + h * 128;
      shortx8 v = *(const shortx8*)&cep[ridx * 268 + col];
      if (EPI == 3) {
        const float* rp = resf + (size_t)grow * M + colbase + col;
        float4 r0 = *(const float4*)rp;
        float4 r1 = *(const float4*)(rp + 4);
        v[0] = f2b(b2f(v[0]) + r0.x); v[1] = f2b(b2f(v[1]) + r0.y);
        v[2] = f2b(b2f(v[2]) + r0.z); v[3] = f2b(b2f(v[3]) + r0.w);
        v[4] = f2b(b2f(v[4]) + r1.x); v[5] = f2b(b2f(v[5]) + r1.y);
        v[6] = f2b(b2f(v[6]) + r1.z); v[7] = f2b(b2f(v[7]) + r1.w);
      } else if (EPI == 5) {
        shortx8 rv = *(const shortx8*)(resb + (size_t)grow * M + colbase + col);
#pragma unroll
        for (int k = 0; k < 8; k++) v[k] = f2b(b2f(v[k]) + b2f(rv[k]));
      }
      *(shortx8*)(ob + (size_t)grow * M + colbase + col) = v;
    }
  }
}

// ---------------------------------------------------------------------------
// context via MFMA: ctx[bh,d,e] = sum_s phiK[s,b,h*64+d] * V[s,b,h*64+e]
//                   ksum[bh,d]  = sum_s phiK[s,b,h*64+d]  (ones-B MFMA)
// ---------------------------------------------------------------------------
__global__ __launch_bounds__(256) void ctx_mfma(const bf16* __restrict__ phiK,
                                                const bf16* __restrict__ V,
                                                float* __restrict__ ctx,
                                                float* __restrict__ ksum) {
  __shared__ __align__(16) short sKT[64][72];
  __shared__ __align__(16) short sVT[64][72];
  const int bh = blockIdx.x, b = bh >> 4, h = bh & 15;
  const int t = threadIdx.x, lane = t & 63, wave = t >> 6;
  const int s_l = t >> 2;
  const int c0 = (t & 3) << 4;
  const int frow = lane & 15, fk = (lane >> 4) << 3;
  const shortx8 ones = (shortx8)(short)0x3F80;
  floatx4 acc[4] = {};
  floatx4 accK = {};

  const int sbeg = blockIdx.y * 512;
  for (int sub = 0; sub < 8; sub++) {
    const size_t g = ((size_t)(sbeg + sub * 64 + s_l) * 4 + b) * 1024 + h * 64 + c0;
    shortx8 kv0 = *(const shortx8*)(phiK + g);
    shortx8 kv1 = *(const shortx8*)(phiK + g + 8);
    shortx8 vv0 = *(const shortx8*)(V + g);
    shortx8 vv1 = *(const shortx8*)(V + g + 8);
    __syncthreads();
#pragma unroll
    for (int j = 0; j < 8; j++) {
      sKT[c0 + j][s_l] = kv0[j];
      sKT[c0 + 8 + j][s_l] = kv1[j];
      sVT[c0 + j][s_l] = vv0[j];
      sVT[c0 + 8 + j][s_l] = vv1[j];
    }
    __syncthreads();
#pragma unroll
    for (int ks = 0; ks < 2; ks++) {
      shortx8 af = *(const shortx8*)&sKT[wave * 16 + frow][ks * 32 + fk];
      accK = MFMA16(af, ones, accK);
#pragma unroll
      for (int j = 0; j < 4; j++) {
        shortx8 bfr = *(const shortx8*)&sVT[j * 16 + frow][ks * 32 + fk];
        acc[j] = MFMA16(af, bfr, acc[j]);
      }
    }
  }

  float* cdst = ctx + (size_t)bh * 4096;
  const int dr0 = wave * 16 + ((lane >> 4) << 2);
  const int e = lane & 15;
#pragma unroll
  for (int j = 0; j < 4; j++)
#pragma unroll
    for (int r = 0; r < 4; r++)
      atomicAdd(cdst + (size_t)(dr0 + r) * 64 + j * 16 + e, acc[j][r]);
  if (e == 0) {
#pragma unroll
    for (int r = 0; r < 4; r++) atomicAdd(ksum + bh * 64 + dr0 + r, accK[r]);
  }
}

// ---------------------------------------------------------------------------
// apply: out[s,b,h*64+e] = (phiQ[s,:].ctx[:,e]) / (phiQ[s,:].ksum + eps)
// ---------------------------------------------------------------------------
__global__ __launch_bounds__(256) void attn_mfma(const bf16* __restrict__ phiQ,
                                                 const float* __restrict__ ctx,
                                                 const float* __restrict__ ksum,
                                                 bf16* __restrict__ attn) {
  __shared__ __align__(16) bf16 sctxT[64][72];
  __shared__ __align__(16) bf16 sks[64];
  const int bh = blockIdx.x, b = bh >> 4, h = bh & 15;
  const int t = threadIdx.x, lane = t & 63, wave = t >> 6;
  const float* cbase = ctx + (size_t)bh * 4096;
  for (int idx = t; idx < 4096; idx += 256) {
    int d = idx >> 6, e = idx & 63;
    sctxT[e][d] = __float2bfloat16(cbase[idx]);
  }
  if (t < 64) sks[t] = __float2bfloat16(ksum[bh * 64 + t]);
  __syncthreads();

  const int s0 = blockIdx.y * 128 + wave * 32;
  const int frow = lane & 15, fk = (lane >> 4) << 3;
  shortx8 bfr[2][4], kfr[2];
#pragma unroll
  for (int ks = 0; ks < 2; ks++) {
#pragma unroll
    for (int j = 0; j < 4; j++) bfr[ks][j] = *(const shortx8*)&sctxT[j * 16 + frow][ks * 32 + fk];
    kfr[ks] = *(const shortx8*)&sks[ks * 32 + fk];
  }
  floatx4 acc[2][4] = {};
  floatx4 accd[2] = {};
#pragma unroll
  for (int i = 0; i < 2; i++) {
#pragma unroll
    for (int ks = 0; ks < 2; ks++) {
      const int srow = s0 + i * 16 + frow;
      const bf16* ap = phiQ + ((size_t)srow * 4 + b) * 1024 + h * 64 + ks * 32 + fk;
      shortx8 af = *(const shortx8*)ap;
#pragma unroll
      for (int j = 0; j < 4; j++) acc[i][j] = MFMA16(af, bfr[ks][j], acc[i][j]);
      accd[i] = MFMA16(af, kfr[ks], accd[i]);
    }
  }
#pragma unroll
  for (int i = 0; i < 2; i++) {
#pragma unroll
    for (int r = 0; r < 4; r++) {
      const int srow = s0 + i * 16 + ((lane >> 4) << 2) + r;
      const float den = accd[i][r] + 1e-6f;
#pragma unroll
      for (int j = 0; j < 4; j++) {
        const int e = j * 16 + (lane & 15);
        attn[((size_t)srow * 4 + b) * 1024 + h * 64 + e] = __float2bfloat16(acc[i][j][r] / den);
      }
    }
  }
}

// ---------------------------------------------------------------------------
// layernorm over D=1024, bf16 input: block per row, 256 threads x 4.
// writes bf16 (outb) or fp32 (outf).
// ---------------------------------------------------------------------------
__global__ __launch_bounds__(256) void ln_kernel(const bf16* __restrict__ x,
                                                 const float* __restrict__ g,
                                                 const float* __restrict__ be,
                                                 bf16* __restrict__ outb,
                                                 float* __restrict__ outf) {
  const int row = blockIdx.x, t = threadIdx.x;
  const ushort4 u = ((const ushort4*)(x + (size_t)row * 1024))[t];
  float v0 = b2f((short)u.x), v1 = b2f((short)u.y);
  float v2 = b2f((short)u.z), v3 = b2f((short)u.w);
  float s = v0 + v1 + v2 + v3;
  float q = v0 * v0 + v1 * v1 + v2 * v2 + v3 * v3;
#pragma unroll
  for (int off = 32; off; off >>= 1) {
    s += __shfl_xor(s, off);
    q += __shfl_xor(q, off);
  }
  __shared__ float ss[4], sq[4];
  const int wave = t >> 6;
  if ((t & 63) == 0) { ss[wave] = s; sq[wave] = q; }
  __syncthreads();
  s = ss[0] + ss[1] + ss[2] + ss[3];
  q = sq[0] + sq[1] + sq[2] + sq[3];
  const float mu = s * (1.f / 1024.f);
  const float var = q * (1.f / 1024.f) - mu * mu;
  const float rstd = rsqrtf(var + 1e-5f);
  const float4 gv = ((const float4*)g)[t];
  const float4 bv = ((const float4*)be)[t];
  float y0 = (v0 - mu) * rstd * gv.x + bv.x;
  float y1 = (v1 - mu) * rstd * gv.y + bv.y;
  float y2 = (v2 - mu) * rstd * gv.z + bv.z;
  float y3 = (v3 - mu) * rstd * gv.w + bv.w;
  if (outb != nullptr) {
    ushort4 o;
    o.x = (unsigned short)f2b(y0); o.y = (unsigned short)f2b(y1);
    o.z = (unsigned short)f2b(y2); o.w = (unsigned short)f2b(y3);
    ((ushort4*)(outb + (size_t)row * 1024))[t] = o;
  } else {
    float4 o = {y0, y1, y2, y3};
    ((float4*)(outf + (size_t)row * 1024))[t] = o;
  }
}

// ---------------------------------------------------------------------------
extern "C" void kernel_launch(void* const* d_in, const int* in_sizes, int n_in,
                              void* d_out, int out_size, void* d_ws, size_t ws_size,
                              hipStream_t stream) {
  const float* src = (const float*)d_in[0];
  const float* Wq = (const float*)d_in[1];
  const float* bq = (const float*)d_in[2];
  const float* Wk = (const float*)d_in[3];
  const float* bk = (const float*)d_in[4];
  const float* Wv = (const float*)d_in[5];
  const float* bv = (const float*)d_in[6];
  const float* Wo = (const float*)d_in[7];
  const float* bo = (const float*)d_in[8];
  const float* W1 = (const float*)d_in[9];
  const float* b1 = (const float*)d_in[10];
  const float* W2 = (const float*)d_in[11];
  const float* b2 = (const float*)d_in[12];
  const float* g1 = (const float*)d_in[13];
  const float* be1 = (const float*)d_in[14];
  const float* g2 = (const float*)d_in[15];
  const float* be2 = (const float*)d_in[16];

  const size_t MB = 1024 * 1024;
  char* w = (char*)d_ws;
  bf16* src_bf = (bf16*)(w + 0);          // 32 MB, dead after QKV GEMM
  bf16* x1b = (bf16*)(w + 0);             // 32 MB (src + attn@Wo, bf16), after QKV
  bf16* phiQ = (bf16*)(w + 64 * MB);      // 32 MB
  bf16* phiK = (bf16*)(w + 96 * MB);      // 32 MB, dead after ctx
  bf16* attn = (bf16*)(w + 96 * MB);      // 32 MB
  bf16* Vb = (bf16*)(w + 128 * MB);       // 32 MB, dead after ctx
  bf16* out1b = (bf16*)(w + 128 * MB);    // 32 MB (LN1 out, FFN2 residual)
  bf16* x2b = (bf16*)(w + 160 * MB);      // 32 MB (out1 + ffn, bf16)
  bf16* Wq_b = (bf16*)(w + 224 * MB);     // Wq/Wk/Wv contiguous
  bf16* Wk_b = (bf16*)(w + 226 * MB);
  bf16* Wv_b = (bf16*)(w + 228 * MB);
  bf16* Wo_b = (bf16*)(w + 230 * MB);
  bf16* W1_b = (bf16*)(w + 232 * MB);
  bf16* W2_b = (bf16*)(w + 236 * MB);
  float* ctx = (float*)(w + 240 * MB);
  float* ksum = (float*)(w + 241 * MB);
  bf16* H1 = (bf16*)d_out;                // 16384x2048 bf16 scratch in d_out
  float* outf = (float*)d_out;

  const dim3 blk(256), blk5(512);
  f2b_all<<<24576, blk, 0, stream>>>(src, Wq, Wk, Wv, Wo, W1, W2, src_bf, Wq_b,
                                     Wk_b, Wv_b, Wo_b, W1_b, W2_b);
  hipMemsetAsync(ctx, 0, (64 * 64 * 64 + 64 * 64) * sizeof(float), stream);

  // fused QKV: B = [Wq;Wk;Wv] (3072 rows), sel block-uniform per bn tile
  gemm256<4><<<dim3(64, 12), blk5, 0, stream>>>(
      src_bf, Wq_b, bq, bk, bv, nullptr, nullptr, phiQ, phiK, Vb, 1024, 1024);
  ctx_mfma<<<dim3(64, 8), blk, 0, stream>>>(phiK, Vb, ctx, ksum);
  attn_mfma<<<dim3(64, 32), blk, 0, stream>>>(phiQ, ctx, ksum, attn);
  // out projection + residual(src fp32) -> bf16
  gemm256<3><<<dim3(64, 4), blk5, 0, stream>>>(
      attn, Wo_b, bo, nullptr, nullptr, src, nullptr, x1b, nullptr, nullptr, 1024, 1024);
  ln_kernel<<<16384, blk, 0, stream>>>(x1b, g1, be1, out1b, nullptr);
  // FFN
  gemm256<2><<<dim3(64, 8), blk5, 0, stream>>>(
      out1b, W1_b, b1, nullptr, nullptr, nullptr, nullptr, H1, nullptr, nullptr, 2048, 1024);
  gemm256<5><<<dim3(64, 4), blk5, 0, stream>>>(
      H1, W2_b, b2, nullptr, nullptr, nullptr, out1b, x2b, nullptr, nullptr, 1024, 2048);
  ln_kernel<<<16384, blk, 0, stream>>>(x2b, g2, be2, nullptr, outf);
}

// Round 10
// 531.778 us; speedup vs baseline: 6.0545x; 6.0545x over previous
//
#include <hip/hip_runtime.h>
#include <hip/hip_bf16.h>

typedef __hip_bfloat16 bf16;
typedef __attribute__((ext_vector_type(4))) float floatx4;
typedef __attribute__((ext_vector_type(8))) short shortx8;

#define MFMA16(a, b, c) __builtin_amdgcn_mfma_f32_16x16x32_bf16(a, b, c, 0, 0, 0)

__device__ __forceinline__ void gll16(const bf16* g, void* l) {
  __builtin_amdgcn_global_load_lds((const __attribute__((address_space(1))) unsigned int*)g,
                                   (__attribute__((address_space(3))) unsigned int*)l,
                                   16, 0, 0);
}

// inline-asm LDS read: invisible to the compiler's waitcnt pass so the
// counted-vmcnt pipeline is not broken by auto-inserted drains. Ordering is
// restored manually via s_waitcnt lgkmcnt(0) + sched_barrier(0) (rule 18).
__device__ __forceinline__ shortx8 ds8(const char* p) {
  shortx8 r;
  unsigned a = (unsigned)(unsigned long long)(const __attribute__((address_space(3))) char*)p;
  asm volatile("ds_read_b128 %0, %1" : "=v"(r) : "v"(a));
  return r;
}

__device__ __forceinline__ float b2f(short s) {
  return __bfloat162float(__builtin_bit_cast(bf16, (unsigned short)s));
}
__device__ __forceinline__ short f2b(float f) {
  return __builtin_bit_cast(short, __float2bfloat16(f));
}

// ---------------------------------------------------------------------------
// fused fp32 -> bf16 converts: src (16384 blks) + 6 weights (8192 blks)
// ---------------------------------------------------------------------------
__global__ __launch_bounds__(256) void f2b_all(
    const float* __restrict__ src, const float* __restrict__ Wq,
    const float* __restrict__ Wk, const float* __restrict__ Wv,
    const float* __restrict__ Wo, const float* __restrict__ W1,
    const float* __restrict__ W2, bf16* __restrict__ src_bf,
    bf16* __restrict__ Wq_b, bf16* __restrict__ Wk_b, bf16* __restrict__ Wv_b,
    bf16* __restrict__ Wo_b, bf16* __restrict__ W1_b, bf16* __restrict__ W2_b) {
  const int blk = blockIdx.x;
  const float* in;
  bf16* out;
  int off;
  if (blk < 16384)      { in = src; out = src_bf; off = blk; }
  else if (blk < 17408) { in = Wq; out = Wq_b; off = blk - 16384; }
  else if (blk < 18432) { in = Wk; out = Wk_b; off = blk - 17408; }
  else if (blk < 19456) { in = Wv; out = Wv_b; off = blk - 18432; }
  else if (blk < 20480) { in = Wo; out = Wo_b; off = blk - 19456; }
  else if (blk < 22528) { in = W1; out = W1_b; off = blk - 20480; }
  else                  { in = W2; out = W2_b; off = blk - 22528; }
  const int i = (off * 256 + threadIdx.x) * 4;
  float4 v = *(const float4*)(in + i);
  ushort4 u;
  u.x = (unsigned short)f2b(v.x);
  u.y = (unsigned short)f2b(v.y);
  u.z = (unsigned short)f2b(v.z);
  u.w = (unsigned short)f2b(v.w);
  *(ushort4*)(out + i) = u;
}

// ---------------------------------------------------------------------------
// NT GEMM, 256x256 tile, BK=32, 512 threads (8 waves 2Mx4N), 4-deep K-tile
// LDS ring (128 KiB), counted-vmcnt pipeline (T3+T4), setprio around MFMA
// clusters (T5), chunk-XOR LDS swizzle (T2: SQ_LDS_BANK_CONFLICT == 0).
//
// Schedule per K-tile t (2 phases):
//   ph0: ds_read B j0..3 + A i0..3 ; stage A(t+3) ; s_barrier ; lgkmcnt(0) ;
//        setprio(1) ; 16 MFMA ; setprio(0)
//   ph1: ds_read A i4..7          ; stage B(t+3) ; s_barrier ; lgkmcnt(0) ;
//        setprio(1) ; 16 MFMA ; setprio(0)
//   end: s_waitcnt vmcnt(8) (-> 4 -> 0 in last 3 tiles) ; s_barrier
// vmcnt(8) with 12 outstanding (4 gll/wave/tile x 3 tiles) drains exactly
// tile t+1's 4 loads -- the optimal m218-formula count (round-9 ERRATA:
// "12" was a miscount of loads/tile and raced; 8 is correct AND minimal).
// Session-verified best: 532.8 us total, QKV 121.5 us, 0 bank conflicts.
//
// EPI: 1 id->bf16 ; 2 relu->bf16 ; 3 +res(fp32)->bf16 ; 4 fused QKV
//      (block-uniform sel: phi->phiQ/phiK, id->V) ; 5 +res(bf16)->bf16
// ---------------------------------------------------------------------------
template <int EPI>
__global__ __launch_bounds__(512, 2) void gemm256(
    const bf16* __restrict__ A, const bf16* __restrict__ Bw,
    const float* __restrict__ bias0, const float* __restrict__ bias1,
    const float* __restrict__ bias2, const float* __restrict__ resf,
    const bf16* __restrict__ resb, void* __restrict__ out0,
    void* __restrict__ out1, void* __restrict__ out2, const int M,
    const int K) {
  __shared__ __align__(16) char smem[131072];  // A: 4x16KB @0, B: 4x16KB @65536
  const int tid = threadIdx.x;
  const int lane = tid & 63, wave = tid >> 6;
  const int wm = wave & 1, wn = wave >> 1;
  const int bm = blockIdx.x, bn = blockIdx.y;
  const int NK = K >> 5;

  // staging: thread -> (row = tid>>2 in a 128-row half, lds chunk = tid&3),
  // source chunk pre-swizzled so linear global_load_lds dest yields the
  // swizzled layout (rule 21).
  const int srow = tid >> 2;
  const int schunk = (tid & 3) ^ ((srow >> 1) & 3);
  const bf16* gA0 = A + (size_t)(bm * 256 + srow) * K + schunk * 8;
  const bf16* gA1 = gA0 + (size_t)128 * K;
  const bf16* gB0 = Bw + (size_t)(bn * 256 + srow) * K + schunk * 8;
  const bf16* gB1 = gB0 + (size_t)128 * K;
  const unsigned ldst = (unsigned)wave * 1024u;  // wave-uniform

  // fragment-read offsets (swizzled chunk on read side)
  const int frow = lane & 15;
  const unsigned fch16 = (unsigned)(((lane >> 4) ^ ((frow >> 1) & 3))) << 4;
  const unsigned aoff0 = (unsigned)(wm * 8192 + frow * 64) + fch16;
  const unsigned boff0 = 65536u + (unsigned)(wn * 4096 + frow * 64) + fch16;

  floatx4 acc[8][4] = {};

#define STAGE_A(t)                                                       \
  {                                                                      \
    const int kk = (t) * 32;                                             \
    const unsigned bo = (unsigned)(((t) & 3) * 16384) + ldst;            \
    gll16(gA0 + kk, smem + bo);                                          \
    gll16(gA1 + kk, smem + bo + 8192);                                   \
  }
#define STAGE_B(t)                                                       \
  {                                                                      \
    const int kk = (t) * 32;                                             \
    const unsigned bo = 65536u + (unsigned)(((t) & 3) * 16384) + ldst;   \
    gll16(gB0 + kk, smem + bo);                                          \
    gll16(gB1 + kk, smem + bo + 8192);                                   \
  }

  // prologue: tiles 0,1,2 in flight (12 loads); tile 0 resident after vmcnt(8)
  STAGE_A(0); STAGE_B(0);
  STAGE_A(1); STAGE_B(1);
  STAGE_A(2); STAGE_B(2);
  asm volatile("s_waitcnt vmcnt(8)");
  __builtin_amdgcn_sched_barrier(0);
  __builtin_amdgcn_s_barrier();

  for (int kt = 0; kt < NK; ++kt) {
    const unsigned ab = aoff0 + (unsigned)((kt & 3) * 16384);
    const unsigned bb = boff0 + (unsigned)((kt & 3) * 16384);
    shortx8 bfr[4], af[4];
    // ---- phase 0 ----
#pragma unroll
    for (int j = 0; j < 4; j++) bfr[j] = ds8(smem + bb + j * 1024);
#pragma unroll
    for (int i2 = 0; i2 < 4; i2++) af[i2] = ds8(smem + ab + i2 * 1024);
    if (kt + 3 < NK) STAGE_A(kt + 3);
    __builtin_amdgcn_s_barrier();
    asm volatile("s_waitcnt lgkmcnt(0)");
    __builtin_amdgcn_sched_barrier(0);
    __builtin_amdgcn_s_setprio(1);
#pragma unroll
    for (int i2 = 0; i2 < 4; i2++)
#pragma unroll
      for (int j = 0; j < 4; j++) acc[i2][j] = MFMA16(af[i2], bfr[j], acc[i2][j]);
    __builtin_amdgcn_s_setprio(0);
    // ---- phase 1 ----
#pragma unroll
    for (int i2 = 0; i2 < 4; i2++) af[i2] = ds8(smem + ab + (4 + i2) * 1024);
    if (kt + 3 < NK) STAGE_B(kt + 3);
    __builtin_amdgcn_s_barrier();
    asm volatile("s_waitcnt lgkmcnt(0)");
    __builtin_amdgcn_sched_barrier(0);
    __builtin_amdgcn_s_setprio(1);
#pragma unroll
    for (int i2 = 0; i2 < 4; i2++)
#pragma unroll
      for (int j = 0; j < 4; j++)
        acc[4 + i2][j] = MFMA16(af[i2], bfr[j], acc[4 + i2][j]);
    __builtin_amdgcn_s_setprio(0);
    // ---- end of tile: gate tile kt+1 residency (counted; optimal N=8) ----
    if (kt < NK - 1) {
      if (kt < NK - 3) {
        asm volatile("s_waitcnt vmcnt(8)");
      } else if (kt == NK - 3) {
        asm volatile("s_waitcnt vmcnt(4)");
      } else {
        asm volatile("s_waitcnt vmcnt(0)");
      }
      __builtin_amdgcn_sched_barrier(0);
      __builtin_amdgcn_s_barrier();
    }
  }
#undef STAGE_A
#undef STAGE_B

  // ---- epilogue: fragments -> LDS -> coalesced 16-B row-linear stores ----
  // stride 268 shorts (536 B): measured 0 bank conflicts.
  bf16* cep = (bf16*)smem;  // [32][268]
  const float* bptr = bias0;
  bf16* ob = (bf16*)out0;
  int colbase = bn * 256;
  int phi = 0;
  if (EPI == 4) {
    const int sel = bn >> 2;
    bptr = (sel == 0) ? bias0 : (sel == 1) ? bias1 : bias2;
    ob = (bf16*)((sel == 0) ? out0 : (sel == 1) ? out1 : out2);
    colbase = (bn & 3) * 256;
    phi = (sel < 2);
  }
  const int e = lane & 15, q4 = (lane >> 4) << 2;
  float bj[4];
#pragma unroll
  for (int j = 0; j < 4; j++) bj[j] = bptr[colbase + wn * 64 + j * 16 + e];

  const int ridx = tid >> 4;      // 0..31
  const int cc = (tid & 15) * 8;  // 0..120
  const int grow_base = bm * 256 + (ridx >> 4) * 128 + (ridx & 15);

#pragma unroll
  for (int i3 = 0; i3 < 8; i3++) {
    __syncthreads();
#pragma unroll
    for (int j = 0; j < 4; j++)
#pragma unroll
      for (int r = 0; r < 4; r++) {
        float v = acc[i3][j][r] + bj[j];
        if (EPI == 4 && phi) v = v > 0.f ? v + 1.f : __expf(v);
        if (EPI == 2) v = fmaxf(v, 0.f);
        cep[(wm * 16 + q4 + r) * 268 + wn * 64 + j * 16 + e] =
            __builtin_bit_cast(bf16, f2b(v));
      }
    __syncthreads();
    const int grow = grow_base + i3 * 16;
#pragma unroll
    for (int h = 0; h < 2; h++) {
      const int col = cc + h * 128;
      shortx8 v = *(const shortx8*)&cep[ridx * 268 + col];
      if (EPI == 3) {
        const float* rp = resf + (size_t)grow * M + colbase + col;
        float4 r0 = *(const float4*)rp;
        float4 r1 = *(const float4*)(rp + 4);
        v[0] = f2b(b2f(v[0]) + r0.x); v[1] = f2b(b2f(v[1]) + r0.y);
        v[2] = f2b(b2f(v[2]) + r0.z); v[3] = f2b(b2f(v[3]) + r0.w);
        v[4] = f2b(b2f(v[4]) + r1.x); v[5] = f2b(b2f(v[5]) + r1.y);
        v[6] = f2b(b2f(v[6]) + r1.z); v[7] = f2b(b2f(v[7]) + r1.w);
      } else if (EPI == 5) {
        shortx8 rv = *(const shortx8*)(resb + (size_t)grow * M + colbase + col);
#pragma unroll
        for (int k = 0; k < 8; k++) v[k] = f2b(b2f(v[k]) + b2f(rv[k]));
      }
      *(shortx8*)(ob + (size_t)grow * M + colbase + col) = v;
    }
  }
}

// ---------------------------------------------------------------------------
// context via MFMA: ctx[bh,d,e] = sum_s phiK[s,b,h*64+d] * V[s,b,h*64+e]
//                   ksum[bh,d]  = sum_s phiK[s,b,h*64+d]  (ones-B MFMA)
// ---------------------------------------------------------------------------
__global__ __launch_bounds__(256) void ctx_mfma(const bf16* __restrict__ phiK,
                                                const bf16* __restrict__ V,
                                                float* __restrict__ ctx,
                                                float* __restrict__ ksum) {
  __shared__ __align__(16) short sKT[64][72];
  __shared__ __align__(16) short sVT[64][72];
  const int bh = blockIdx.x, b = bh >> 4, h = bh & 15;
  const int t = threadIdx.x, lane = t & 63, wave = t >> 6;
  const int s_l = t >> 2;
  const int c0 = (t & 3) << 4;
  const int frow = lane & 15, fk = (lane >> 4) << 3;
  const shortx8 ones = (shortx8)(short)0x3F80;
  floatx4 acc[4] = {};
  floatx4 accK = {};

  const int sbeg = blockIdx.y * 512;
  for (int sub = 0; sub < 8; sub++) {
    const size_t g = ((size_t)(sbeg + sub * 64 + s_l) * 4 + b) * 1024 + h * 64 + c0;
    shortx8 kv0 = *(const shortx8*)(phiK + g);
    shortx8 kv1 = *(const shortx8*)(phiK + g + 8);
    shortx8 vv0 = *(const shortx8*)(V + g);
    shortx8 vv1 = *(const shortx8*)(V + g + 8);
    __syncthreads();
#pragma unroll
    for (int j = 0; j < 8; j++) {
      sKT[c0 + j][s_l] = kv0[j];
      sKT[c0 + 8 + j][s_l] = kv1[j];
      sVT[c0 + j][s_l] = vv0[j];
      sVT[c0 + 8 + j][s_l] = vv1[j];
    }
    __syncthreads();
#pragma unroll
    for (int ks = 0; ks < 2; ks++) {
      shortx8 af = *(const shortx8*)&sKT[wave * 16 + frow][ks * 32 + fk];
      accK = MFMA16(af, ones, accK);
#pragma unroll
      for (int j = 0; j < 4; j++) {
        shortx8 bfr = *(const shortx8*)&sVT[j * 16 + frow][ks * 32 + fk];
        acc[j] = MFMA16(af, bfr, acc[j]);
      }
    }
  }

  float* cdst = ctx + (size_t)bh * 4096;
  const int dr0 = wave * 16 + ((lane >> 4) << 2);
  const int e = lane & 15;
#pragma unroll
  for (int j = 0; j < 4; j++)
#pragma unroll
    for (int r = 0; r < 4; r++)
      atomicAdd(cdst + (size_t)(dr0 + r) * 64 + j * 16 + e, acc[j][r]);
  if (e == 0) {
#pragma unroll
    for (int r = 0; r < 4; r++) atomicAdd(ksum + bh * 64 + dr0 + r, accK[r]);
  }
}

// ---------------------------------------------------------------------------
// apply: out[s,b,h*64+e] = (phiQ[s,:].ctx[:,e]) / (phiQ[s,:].ksum + eps)
// ---------------------------------------------------------------------------
__global__ __launch_bounds__(256) void attn_mfma(const bf16* __restrict__ phiQ,
                                                 const float* __restrict__ ctx,
                                                 const float* __restrict__ ksum,
                                                 bf16* __restrict__ attn) {
  __shared__ __align__(16) bf16 sctxT[64][72];
  __shared__ __align__(16) bf16 sks[64];
  const int bh = blockIdx.x, b = bh >> 4, h = bh & 15;
  const int t = threadIdx.x, lane = t & 63, wave = t >> 6;
  const float* cbase = ctx + (size_t)bh * 4096;
  for (int idx = t; idx < 4096; idx += 256) {
    int d = idx >> 6, e = idx & 63;
    sctxT[e][d] = __float2bfloat16(cbase[idx]);
  }
  if (t < 64) sks[t] = __float2bfloat16(ksum[bh * 64 + t]);
  __syncthreads();

  const int s0 = blockIdx.y * 128 + wave * 32;
  const int frow = lane & 15, fk = (lane >> 4) << 3;
  shortx8 bfr[2][4], kfr[2];
#pragma unroll
  for (int ks = 0; ks < 2; ks++) {
#pragma unroll
    for (int j = 0; j < 4; j++) bfr[ks][j] = *(const shortx8*)&sctxT[j * 16 + frow][ks * 32 + fk];
    kfr[ks] = *(const shortx8*)&sks[ks * 32 + fk];
  }
  floatx4 acc[2][4] = {};
  floatx4 accd[2] = {};
#pragma unroll
  for (int i = 0; i < 2; i++) {
#pragma unroll
    for (int ks = 0; ks < 2; ks++) {
      const int srow = s0 + i * 16 + frow;
      const bf16* ap = phiQ + ((size_t)srow * 4 + b) * 1024 + h * 64 + ks * 32 + fk;
      shortx8 af = *(const shortx8*)ap;
#pragma unroll
      for (int j = 0; j < 4; j++) acc[i][j] = MFMA16(af, bfr[ks][j], acc[i][j]);
      accd[i] = MFMA16(af, kfr[ks], accd[i]);
    }
  }
#pragma unroll
  for (int i = 0; i < 2; i++) {
#pragma unroll
    for (int r = 0; r < 4; r++) {
      const int srow = s0 + i * 16 + ((lane >> 4) << 2) + r;
      const float den = accd[i][r] + 1e-6f;
#pragma unroll
      for (int j = 0; j < 4; j++) {
        const int e = j * 16 + (lane & 15);
        attn[((size_t)srow * 4 + b) * 1024 + h * 64 + e] = __float2bfloat16(acc[i][j][r] / den);
      }
    }
  }
}

// ---------------------------------------------------------------------------
// layernorm over D=1024, bf16 input: block per row, 256 threads x 4.
// writes bf16 (outb) or fp32 (outf).
// ---------------------------------------------------------------------------
__global__ __launch_bounds__(256) void ln_kernel(const bf16* __restrict__ x,
                                                 const float* __restrict__ g,
                                                 const float* __restrict__ be,
                                                 bf16* __restrict__ outb,
                                                 float* __restrict__ outf) {
  const int row = blockIdx.x, t = threadIdx.x;
  const ushort4 u = ((const ushort4*)(x + (size_t)row * 1024))[t];
  float v0 = b2f((short)u.x), v1 = b2f((short)u.y);
  float v2 = b2f((short)u.z), v3 = b2f((short)u.w);
  float s = v0 + v1 + v2 + v3;
  float q = v0 * v0 + v1 * v1 + v2 * v2 + v3 * v3;
#pragma unroll
  for (int off = 32; off; off >>= 1) {
    s += __shfl_xor(s, off);
    q += __shfl_xor(q, off);
  }
  __shared__ float ss[4], sq[4];
  const int wave = t >> 6;
  if ((t & 63) == 0) { ss[wave] = s; sq[wave] = q; }
  __syncthreads();
  s = ss[0] + ss[1] + ss[2] + ss[3];
  q = sq[0] + sq[1] + sq[2] + sq[3];
  const float mu = s * (1.f / 1024.f);
  const float var = q * (1.f / 1024.f) - mu * mu;
  const float rstd = rsqrtf(var + 1e-5f);
  const float4 gv = ((const float4*)g)[t];
  const float4 bv = ((const float4*)be)[t];
  float y0 = (v0 - mu) * rstd * gv.x + bv.x;
  float y1 = (v1 - mu) * rstd * gv.y + bv.y;
  float y2 = (v2 - mu) * rstd * gv.z + bv.z;
  float y3 = (v3 - mu) * rstd * gv.w + bv.w;
  if (outb != nullptr) {
    ushort4 o;
    o.x = (unsigned short)f2b(y0); o.y = (unsigned short)f2b(y1);
    o.z = (unsigned short)f2b(y2); o.w = (unsigned short)f2b(y3);
    ((ushort4*)(outb + (size_t)row * 1024))[t] = o;
  } else {
    float4 o = {y0, y1, y2, y3};
    ((float4*)(outf + (size_t)row * 1024))[t] = o;
  }
}

// ---------------------------------------------------------------------------
extern "C" void kernel_launch(void* const* d_in, const int* in_sizes, int n_in,
                              void* d_out, int out_size, void* d_ws, size_t ws_size,
                              hipStream_t stream) {
  const float* src = (const float*)d_in[0];
  const float* Wq = (const float*)d_in[1];
  const float* bq = (const float*)d_in[2];
  const float* Wk = (const float*)d_in[3];
  const float* bk = (const float*)d_in[4];
  const float* Wv = (const float*)d_in[5];
  const float* bv = (const float*)d_in[6];
  const float* Wo = (const float*)d_in[7];
  const float* bo = (const float*)d_in[8];
  const float* W1 = (const float*)d_in[9];
  const float* b1 = (const float*)d_in[10];
  const float* W2 = (const float*)d_in[11];
  const float* b2 = (const float*)d_in[12];
  const float* g1 = (const float*)d_in[13];
  const float* be1 = (const float*)d_in[14];
  const float* g2 = (const float*)d_in[15];
  const float* be2 = (const float*)d_in[16];

  const size_t MB = 1024 * 1024;
  char* w = (char*)d_ws;
  bf16* src_bf = (bf16*)(w + 0);          // 32 MB, dead after QKV GEMM
  bf16* x1b = (bf16*)(w + 0);             // 32 MB (src + attn@Wo, bf16), after QKV
  bf16* phiQ = (bf16*)(w + 64 * MB);      // 32 MB
  bf16* phiK = (bf16*)(w + 96 * MB);      // 32 MB, dead after ctx
  bf16* attn = (bf16*)(w + 96 * MB);      // 32 MB
  bf16* Vb = (bf16*)(w + 128 * MB);       // 32 MB, dead after ctx
  bf16* out1b = (bf16*)(w + 128 * MB);    // 32 MB (LN1 out, FFN2 residual)
  bf16* x2b = (bf16*)(w + 160 * MB);      // 32 MB (out1 + ffn, bf16)
  bf16* Wq_b = (bf16*)(w + 224 * MB);     // Wq/Wk/Wv contiguous
  bf16* Wk_b = (bf16*)(w + 226 * MB);
  bf16* Wv_b = (bf16*)(w + 228 * MB);
  bf16* Wo_b = (bf16*)(w + 230 * MB);
  bf16* W1_b = (bf16*)(w + 232 * MB);
  bf16* W2_b = (bf16*)(w + 236 * MB);
  float* ctx = (float*)(w + 240 * MB);
  float* ksum = (float*)(w + 241 * MB);
  bf16* H1 = (bf16*)d_out;                // 16384x2048 bf16 scratch in d_out
  float* outf = (float*)d_out;

  const dim3 blk(256), blk5(512);
  f2b_all<<<24576, blk, 0, stream>>>(src, Wq, Wk, Wv, Wo, W1, W2, src_bf, Wq_b,
                                     Wk_b, Wv_b, Wo_b, W1_b, W2_b);
  hipMemsetAsync(ctx, 0, (64 * 64 * 64 + 64 * 64) * sizeof(float), stream);

  // fused QKV: B = [Wq;Wk;Wv] (3072 rows), sel block-uniform per bn tile
  gemm256<4><<<dim3(64, 12), blk5, 0, stream>>>(
      src_bf, Wq_b, bq, bk, bv, nullptr, nullptr, phiQ, phiK, Vb, 1024, 1024);
  ctx_mfma<<<dim3(64, 8), blk, 0, stream>>>(phiK, Vb, ctx, ksum);
  attn_mfma<<<dim3(64, 32), blk, 0, stream>>>(phiQ, ctx, ksum, attn);
  // out projection + residual(src fp32) -> bf16
  gemm256<3><<<dim3(64, 4), blk5, 0, stream>>>(
      attn, Wo_b, bo, nullptr, nullptr, src, nullptr, x1b, nullptr, nullptr, 1024, 1024);
  ln_kernel<<<16384, blk, 0, stream>>>(x1b, g1, be1, out1b, nullptr);
  // FFN
  gemm256<2><<<dim3(64, 8), blk5, 0, stream>>>(
      out1b, W1_b, b1, nullptr, nullptr, nullptr, nullptr, H1, nullptr, nullptr, 2048, 1024);
  gemm256<5><<<dim3(64, 4), blk5, 0, stream>>>(
      H1, W2_b, b2, nullptr, nullptr, nullptr, out1b, x2b, nullptr, nullptr, 1024, 2048);
  ln_kernel<<<16384, blk, 0, stream>>>(x2b, g2, be2, nullptr, outf);
}

// Round 11
// 515.136 us; speedup vs baseline: 6.2501x; 1.0323x over previous
//
#include <hip/hip_runtime.h>
#include <hip/hip_bf16.h>

typedef __hip_bfloat16 bf16;
typedef __attribute__((ext_vector_type(4))) float floatx4;
typedef __attribute__((ext_vector_type(8))) short shortx8;

#define MFMA16(a, b, c) __builtin_amdgcn_mfma_f32_16x16x32_bf16(a, b, c, 0, 0, 0)

__device__ __forceinline__ void gll16(const bf16* g, void* l) {
  __builtin_amdgcn_global_load_lds((const __attribute__((address_space(1))) unsigned int*)g,
                                   (__attribute__((address_space(3))) unsigned int*)l,
                                   16, 0, 0);
}

__device__ __forceinline__ float b2f(short s) {
  return __bfloat162float(__builtin_bit_cast(bf16, (unsigned short)s));
}
__device__ __forceinline__ short f2b(float f) {
  return __builtin_bit_cast(short, __float2bfloat16(f));
}

// ---------------------------------------------------------------------------
// fused fp32 -> bf16 converts: src (16384 blks) + 6 weights (8192 blks)
// ---------------------------------------------------------------------------
__global__ __launch_bounds__(256) void f2b_all(
    const float* __restrict__ src, const float* __restrict__ Wq,
    const float* __restrict__ Wk, const float* __restrict__ Wv,
    const float* __restrict__ Wo, const float* __restrict__ W1,
    const float* __restrict__ W2, bf16* __restrict__ src_bf,
    bf16* __restrict__ Wq_b, bf16* __restrict__ Wk_b, bf16* __restrict__ Wv_b,
    bf16* __restrict__ Wo_b, bf16* __restrict__ W1_b, bf16* __restrict__ W2_b) {
  const int blk = blockIdx.x;
  const float* in;
  bf16* out;
  int off;
  if (blk < 16384)      { in = src; out = src_bf; off = blk; }
  else if (blk < 17408) { in = Wq; out = Wq_b; off = blk - 16384; }
  else if (blk < 18432) { in = Wk; out = Wk_b; off = blk - 17408; }
  else if (blk < 19456) { in = Wv; out = Wv_b; off = blk - 18432; }
  else if (blk < 20480) { in = Wo; out = Wo_b; off = blk - 19456; }
  else if (blk < 22528) { in = W1; out = W1_b; off = blk - 20480; }
  else                  { in = W2; out = W2_b; off = blk - 22528; }
  const int i = (off * 256 + threadIdx.x) * 4;
  float4 v = *(const float4*)(in + i);
  ushort4 u;
  u.x = (unsigned short)f2b(v.x);
  u.y = (unsigned short)f2b(v.y);
  u.z = (unsigned short)f2b(v.z);
  u.w = (unsigned short)f2b(v.w);
  *(ushort4*)(out + i) = u;
}

// ---------------------------------------------------------------------------
// NT GEMM, 256x256 tile, BK=64, 512 threads (8 waves 2Mx4N), 2-slot LDS ring
// (2 x 64 KiB), EXACTLY ONE barrier per BK-64 tile.
//
// ROUND-11 RATIONALE: the R6 probe showed the barriered 8-wave lockstep
// skeleton alone costs ~700 cyc/tile over the MFMA floor with ZERO memory
// traffic; every prior schedule kept 3-8 barriers per 64-K. This is the
// minimal-barrier point: per tile {STAGE(t+1) -> slot (t+1)&1 ; plain
// compiler-scheduled LDS reads of tile t from slot t&1 ; 64 MFMA ;
// __syncthreads}. The parity ring makes one barrier sufficient (stage and
// reads touch different slots); the barrier's full vmcnt/lgkm drain is
// WANTED (stage(t+1) was issued a full tile (~2600 cyc) earlier). 16
// barriers per K=1024 vs 96 in the 2-phase BK=32 structure.
//
// Staging at BK=64: row = 128 B = 8 x 16-B chunks. Thread tid -> row
// tid>>3, chunk tid&7, XOR-swizzled on the SOURCE (rule 21):
// LDS[r][c] = global[r][c^(r&7)]. Read side applies the same XOR; lanes
// 0-15 of a ds_read_b128 then stripe all 32 banks at 2 lanes/bank (free).
//
// EPI: 1 id->bf16 ; 2 relu->bf16 ; 3 +res(fp32)->bf16 ; 4 fused QKV
//      (block-uniform sel: phi->phiQ/phiK, id->V) ; 5 +res(bf16)->bf16
// ---------------------------------------------------------------------------
template <int EPI>
__global__ __launch_bounds__(512, 2) void gemm256(
    const bf16* __restrict__ A, const bf16* __restrict__ Bw,
    const float* __restrict__ bias0, const float* __restrict__ bias1,
    const float* __restrict__ bias2, const float* __restrict__ resf,
    const bf16* __restrict__ resb, void* __restrict__ out0,
    void* __restrict__ out1, void* __restrict__ out2, const int M,
    const int K) {
  // slot s (s=kt&1) at s*65536: A 256rows x 128B @0 (32 KB), B @32768
  __shared__ __align__(16) char smem[131072];
  const int tid = threadIdx.x;
  const int lane = tid & 63, wave = tid >> 6;
  const int wm = wave & 1, wn = wave >> 1;
  const int bm = blockIdx.x, bn = blockIdx.y;
  const int NT = K >> 6;  // BK=64 tiles

  // staging: row = tid>>3 (64 rows/gll-group), chunk = tid&7 (8 x 16B),
  // source chunk pre-swizzled: sch = (tid&7) ^ (row&7)  (rule 21)
  const int srow = tid >> 3;
  const int sch = (tid & 7) ^ (srow & 7);
  const bf16* gA0 = A + (size_t)(bm * 256 + srow) * K + sch * 8;
  const bf16* gB0 = Bw + (size_t)(bn * 256 + srow) * K + sch * 8;
  const unsigned ldst = (unsigned)wave * 1024u;  // wave-uniform

  // fragment-read offsets: row r, global chunk c=ks*4+(lane>>4) read at
  // LDS chunk c^(r&7); r&7 == frow&7 (all other row terms are mult of 8/16)
  const int frow = lane & 15, lq = lane >> 4, x7 = frow & 7;
  const unsigned arow = (unsigned)(wm * 128 + frow) * 128u;
  const unsigned brow = 32768u + (unsigned)(wn * 64 + frow) * 128u;
  const unsigned aoffA = arow + (unsigned)((lq ^ x7) * 16);        // ks=0
  const unsigned aoffB = arow + (unsigned)(((4 | lq) ^ x7) * 16);  // ks=1
  const unsigned boffA = brow + (unsigned)((lq ^ x7) * 16);
  const unsigned boffB = brow + (unsigned)(((4 | lq) ^ x7) * 16);

  floatx4 acc[8][4] = {};

#define STAGE(t)                                                           \
  {                                                                        \
    const int kk = (t) * 64;                                               \
    const unsigned so2 = (unsigned)(((t) & 1) * 65536);                    \
    gll16(gA0 + kk, smem + so2 + ldst);                                    \
    gll16(gA0 + (size_t)64 * K + kk, smem + so2 + 8192 + ldst);            \
    gll16(gA0 + (size_t)128 * K + kk, smem + so2 + 16384 + ldst);          \
    gll16(gA0 + (size_t)192 * K + kk, smem + so2 + 24576 + ldst);          \
    gll16(gB0 + kk, smem + so2 + 32768 + ldst);                            \
    gll16(gB0 + (size_t)64 * K + kk, smem + so2 + 40960 + ldst);           \
    gll16(gB0 + (size_t)128 * K + kk, smem + so2 + 49152 + ldst);          \
    gll16(gB0 + (size_t)192 * K + kk, smem + so2 + 57344 + ldst);          \
  }

  STAGE(0);
  __syncthreads();  // stage(0) resident (full drain)

  for (int kt = 0; kt < NT; ++kt) {
    const unsigned so = (unsigned)((kt & 1) * 65536);
    if (kt + 1 < NT) STAGE(kt + 1);  // other slot; disjoint from reads
    shortx8 af[8], bfr[4];
#pragma unroll
    for (int ks = 0; ks < 2; ks++) {
      const unsigned ao = so + (ks ? aoffB : aoffA);
      const unsigned bo = so + (ks ? boffB : boffA);
#pragma unroll
      for (int j = 0; j < 4; j++)
        bfr[j] = *(const shortx8*)(smem + bo + j * 2048);
#pragma unroll
      for (int i = 0; i < 8; i++)
        af[i] = *(const shortx8*)(smem + ao + i * 2048);
#pragma unroll
      for (int i = 0; i < 8; i++)
#pragma unroll
        for (int j = 0; j < 4; j++)
          acc[i][j] = MFMA16(af[i], bfr[j], acc[i][j]);
    }
    __syncthreads();  // ONE barrier/tile: drains stage(kt+1), fences slots
  }
#undef STAGE

  // ---- epilogue: fragments -> LDS -> coalesced 16-B row-linear stores ----
  // stride 268 shorts (536 B): measured 0 bank conflicts.
  bf16* cep = (bf16*)smem;  // [32][268]
  const float* bptr = bias0;
  bf16* ob = (bf16*)out0;
  int colbase = bn * 256;
  int phi = 0;
  if (EPI == 4) {
    const int sel = bn >> 2;
    bptr = (sel == 0) ? bias0 : (sel == 1) ? bias1 : bias2;
    ob = (bf16*)((sel == 0) ? out0 : (sel == 1) ? out1 : out2);
    colbase = (bn & 3) * 256;
    phi = (sel < 2);
  }
  const int e = lane & 15, q4 = (lane >> 4) << 2;
  float bj[4];
#pragma unroll
  for (int j = 0; j < 4; j++) bj[j] = bptr[colbase + wn * 64 + j * 16 + e];

  const int ridx = tid >> 4;      // 0..31
  const int cc = (tid & 15) * 8;  // 0..120
  const int grow_base = bm * 256 + (ridx >> 4) * 128 + (ridx & 15);

#pragma unroll
  for (int i3 = 0; i3 < 8; i3++) {
    __syncthreads();
#pragma unroll
    for (int j = 0; j < 4; j++)
#pragma unroll
      for (int r = 0; r < 4; r++) {
        float v = acc[i3][j][r] + bj[j];
        if (EPI == 4 && phi) v = v > 0.f ? v + 1.f : __expf(v);
        if (EPI == 2) v = fmaxf(v, 0.f);
        cep[(wm * 16 + q4 + r) * 268 + wn * 64 + j * 16 + e] =
            __builtin_bit_cast(bf16, f2b(v));
      }
    __syncthreads();
    const int grow = grow_base + i3 * 16;
#pragma unroll
    for (int h = 0; h < 2; h++) {
      const int col = cc + h * 128;
      shortx8 v = *(const shortx8*)&cep[ridx * 268 + col];
      if (EPI == 3) {
        const float* rp = resf + (size_t)grow * M + colbase + col;
        float4 r0 = *(const float4*)rp;
        float4 r1 = *(const float4*)(rp + 4);
        v[0] = f2b(b2f(v[0]) + r0.x); v[1] = f2b(b2f(v[1]) + r0.y);
        v[2] = f2b(b2f(v[2]) + r0.z); v[3] = f2b(b2f(v[3]) + r0.w);
        v[4] = f2b(b2f(v[4]) + r1.x); v[5] = f2b(b2f(v[5]) + r1.y);
        v[6] = f2b(b2f(v[6]) + r1.z); v[7] = f2b(b2f(v[7]) + r1.w);
      } else if (EPI == 5) {
        shortx8 rv = *(const shortx8*)(resb + (size_t)grow * M + colbase + col);
#pragma unroll
        for (int k = 0; k < 8; k++) v[k] = f2b(b2f(v[k]) + b2f(rv[k]));
      }
      *(shortx8*)(ob + (size_t)grow * M + colbase + col) = v;
    }
  }
}

// ---------------------------------------------------------------------------
// context via MFMA: ctx[bh,d,e] = sum_s phiK[s,b,h*64+d] * V[s,b,h*64+e]
//                   ksum[bh,d]  = sum_s phiK[s,b,h*64+d]  (ones-B MFMA)
// ---------------------------------------------------------------------------
__global__ __launch_bounds__(256) void ctx_mfma(const bf16* __restrict__ phiK,
                                                const bf16* __restrict__ V,
                                                float* __restrict__ ctx,
                                                float* __restrict__ ksum) {
  __shared__ __align__(16) short sKT[64][72];
  __shared__ __align__(16) short sVT[64][72];
  const int bh = blockIdx.x, b = bh >> 4, h = bh & 15;
  const int t = threadIdx.x, lane = t & 63, wave = t >> 6;
  const int s_l = t >> 2;
  const int c0 = (t & 3) << 4;
  const int frow = lane & 15, fk = (lane >> 4) << 3;
  const shortx8 ones = (shortx8)(short)0x3F80;
  floatx4 acc[4] = {};
  floatx4 accK = {};

  const int sbeg = blockIdx.y * 512;
  for (int sub = 0; sub < 8; sub++) {
    const size_t g = ((size_t)(sbeg + sub * 64 + s_l) * 4 + b) * 1024 + h * 64 + c0;
    shortx8 kv0 = *(const shortx8*)(phiK + g);
    shortx8 kv1 = *(const shortx8*)(phiK + g + 8);
    shortx8 vv0 = *(const shortx8*)(V + g);
    shortx8 vv1 = *(const shortx8*)(V + g + 8);
    __syncthreads();
#pragma unroll
    for (int j = 0; j < 8; j++) {
      sKT[c0 + j][s_l] = kv0[j];
      sKT[c0 + 8 + j][s_l] = kv1[j];
      sVT[c0 + j][s_l] = vv0[j];
      sVT[c0 + 8 + j][s_l] = vv1[j];
    }
    __syncthreads();
#pragma unroll
    for (int ks = 0; ks < 2; ks++) {
      shortx8 af = *(const shortx8*)&sKT[wave * 16 + frow][ks * 32 + fk];
      accK = MFMA16(af, ones, accK);
#pragma unroll
      for (int j = 0; j < 4; j++) {
        shortx8 bfr = *(const shortx8*)&sVT[j * 16 + frow][ks * 32 + fk];
        acc[j] = MFMA16(af, bfr, acc[j]);
      }
    }
  }

  float* cdst = ctx + (size_t)bh * 4096;
  const int dr0 = wave * 16 + ((lane >> 4) << 2);
  const int e = lane & 15;
#pragma unroll
  for (int j = 0; j < 4; j++)
#pragma unroll
    for (int r = 0; r < 4; r++)
      atomicAdd(cdst + (size_t)(dr0 + r) * 64 + j * 16 + e, acc[j][r]);
  if (e == 0) {
#pragma unroll
    for (int r = 0; r < 4; r++) atomicAdd(ksum + bh * 64 + dr0 + r, accK[r]);
  }
}

// ---------------------------------------------------------------------------
// apply: out[s,b,h*64+e] = (phiQ[s,:].ctx[:,e]) / (phiQ[s,:].ksum + eps)
// ---------------------------------------------------------------------------
__global__ __launch_bounds__(256) void attn_mfma(const bf16* __restrict__ phiQ,
                                                 const float* __restrict__ ctx,
                                                 const float* __restrict__ ksum,
                                                 bf16* __restrict__ attn) {
  __shared__ __align__(16) bf16 sctxT[64][72];
  __shared__ __align__(16) bf16 sks[64];
  const int bh = blockIdx.x, b = bh >> 4, h = bh & 15;
  const int t = threadIdx.x, lane = t & 63, wave = t >> 6;
  const float* cbase = ctx + (size_t)bh * 4096;
  for (int idx = t; idx < 4096; idx += 256) {
    int d = idx >> 6, e = idx & 63;
    sctxT[e][d] = __float2bfloat16(cbase[idx]);
  }
  if (t < 64) sks[t] = __float2bfloat16(ksum[bh * 64 + t]);
  __syncthreads();

  const int s0 = blockIdx.y * 128 + wave * 32;
  const int frow = lane & 15, fk = (lane >> 4) << 3;
  shortx8 bfr[2][4], kfr[2];
#pragma unroll
  for (int ks = 0; ks < 2; ks++) {
#pragma unroll
    for (int j = 0; j < 4; j++) bfr[ks][j] = *(const shortx8*)&sctxT[j * 16 + frow][ks * 32 + fk];
    kfr[ks] = *(const shortx8*)&sks[ks * 32 + fk];
  }
  floatx4 acc[2][4] = {};
  floatx4 accd[2] = {};
#pragma unroll
  for (int i = 0; i < 2; i++) {
#pragma unroll
    for (int ks = 0; ks < 2; ks++) {
      const int srow = s0 + i * 16 + frow;
      const bf16* ap = phiQ + ((size_t)srow * 4 + b) * 1024 + h * 64 + ks * 32 + fk;
      shortx8 af = *(const shortx8*)ap;
#pragma unroll
      for (int j = 0; j < 4; j++) acc[i][j] = MFMA16(af, bfr[ks][j], acc[i][j]);
      accd[i] = MFMA16(af, kfr[ks], accd[i]);
    }
  }
#pragma unroll
  for (int i = 0; i < 2; i++) {
#pragma unroll
    for (int r = 0; r < 4; r++) {
      const int srow = s0 + i * 16 + ((lane >> 4) << 2) + r;
      const float den = accd[i][r] + 1e-6f;
#pragma unroll
      for (int j = 0; j < 4; j++) {
        const int e = j * 16 + (lane & 15);
        attn[((size_t)srow * 4 + b) * 1024 + h * 64 + e] = __float2bfloat16(acc[i][j][r] / den);
      }
    }
  }
}

// ---------------------------------------------------------------------------
// layernorm over D=1024, bf16 input: block per row, 256 threads x 4.
// writes bf16 (outb) or fp32 (outf).
// ---------------------------------------------------------------------------
__global__ __launch_bounds__(256) void ln_kernel(const bf16* __restrict__ x,
                                                 const float* __restrict__ g,
                                                 const float* __restrict__ be,
                                                 bf16* __restrict__ outb,
                                                 float* __restrict__ outf) {
  const int row = blockIdx.x, t = threadIdx.x;
  const ushort4 u = ((const ushort4*)(x + (size_t)row * 1024))[t];
  float v0 = b2f((short)u.x), v1 = b2f((short)u.y);
  float v2 = b2f((short)u.z), v3 = b2f((short)u.w);
  float s = v0 + v1 + v2 + v3;
  float q = v0 * v0 + v1 * v1 + v2 * v2 + v3 * v3;
#pragma unroll
  for (int off = 32; off; off >>= 1) {
    s += __shfl_xor(s, off);
    q += __shfl_xor(q, off);
  }
  __shared__ float ss[4], sq[4];
  const int wave = t >> 6;
  if ((t & 63) == 0) { ss[wave] = s; sq[wave] = q; }
  __syncthreads();
  s = ss[0] + ss[1] + ss[2] + ss[3];
  q = sq[0] + sq[1] + sq[2] + sq[3];
  const float mu = s * (1.f / 1024.f);
  const float var = q * (1.f / 1024.f) - mu * mu;
  const float rstd = rsqrtf(var + 1e-5f);
  const float4 gv = ((const float4*)g)[t];
  const float4 bv = ((const float4*)be)[t];
  float y0 = (v0 - mu) * rstd * gv.x + bv.x;
  float y1 = (v1 - mu) * rstd * gv.y + bv.y;
  float y2 = (v2 - mu) * rstd * gv.z + bv.z;
  float y3 = (v3 - mu) * rstd * gv.w + bv.w;
  if (outb != nullptr) {
    ushort4 o;
    o.x = (unsigned short)f2b(y0); o.y = (unsigned short)f2b(y1);
    o.z = (unsigned short)f2b(y2); o.w = (unsigned short)f2b(y3);
    ((ushort4*)(outb + (size_t)row * 1024))[t] = o;
  } else {
    float4 o = {y0, y1, y2, y3};
    ((float4*)(outf + (size_t)row * 1024))[t] = o;
  }
}

// ---------------------------------------------------------------------------
extern "C" void kernel_launch(void* const* d_in, const int* in_sizes, int n_in,
                              void* d_out, int out_size, void* d_ws, size_t ws_size,
                              hipStream_t stream) {
  const float* src = (const float*)d_in[0];
  const float* Wq = (const float*)d_in[1];
  const float* bq = (const float*)d_in[2];
  const float* Wk = (const float*)d_in[3];
  const float* bk = (const float*)d_in[4];
  const float* Wv = (const float*)d_in[5];
  const float* bv = (const float*)d_in[6];
  const float* Wo = (const float*)d_in[7];
  const float* bo = (const float*)d_in[8];
  const float* W1 = (const float*)d_in[9];
  const float* b1 = (const float*)d_in[10];
  const float* W2 = (const float*)d_in[11];
  const float* b2 = (const float*)d_in[12];
  const float* g1 = (const float*)d_in[13];
  const float* be1 = (const float*)d_in[14];
  const float* g2 = (const float*)d_in[15];
  const float* be2 = (const float*)d_in[16];

  const size_t MB = 1024 * 1024;
  char* w = (char*)d_ws;
  bf16* src_bf = (bf16*)(w + 0);          // 32 MB, dead after QKV GEMM
  bf16* x1b = (bf16*)(w + 0);             // 32 MB (src + attn@Wo, bf16), after QKV
  bf16* phiQ = (bf16*)(w + 64 * MB);      // 32 MB
  bf16* phiK = (bf16*)(w + 96 * MB);      // 32 MB, dead after ctx
  bf16* attn = (bf16*)(w + 96 * MB);      // 32 MB
  bf16* Vb = (bf16*)(w + 128 * MB);       // 32 MB, dead after ctx
  bf16* out1b = (bf16*)(w + 128 * MB);    // 32 MB (LN1 out, FFN2 residual)
  bf16* x2b = (bf16*)(w + 160 * MB);      // 32 MB (out1 + ffn, bf16)
  bf16* Wq_b = (bf16*)(w + 224 * MB);     // Wq/Wk/Wv contiguous
  bf16* Wk_b = (bf16*)(w + 226 * MB);
  bf16* Wv_b = (bf16*)(w + 228 * MB);
  bf16* Wo_b = (bf16*)(w + 230 * MB);
  bf16* W1_b = (bf16*)(w + 232 * MB);
  bf16* W2_b = (bf16*)(w + 236 * MB);
  float* ctx = (float*)(w + 240 * MB);
  float* ksum = (float*)(w + 241 * MB);
  bf16* H1 = (bf16*)d_out;                // 16384x2048 bf16 scratch in d_out
  float* outf = (float*)d_out;

  const dim3 blk(256), blk5(512);
  f2b_all<<<24576, blk, 0, stream>>>(src, Wq, Wk, Wv, Wo, W1, W2, src_bf, Wq_b,
                                     Wk_b, Wv_b, Wo_b, W1_b, W2_b);
  hipMemsetAsync(ctx, 0, (64 * 64 * 64 + 64 * 64) * sizeof(float), stream);

  // fused QKV: B = [Wq;Wk;Wv] (3072 rows), sel block-uniform per bn tile
  gemm256<4><<<dim3(64, 12), blk5, 0, stream>>>(
      src_bf, Wq_b, bq, bk, bv, nullptr, nullptr, phiQ, phiK, Vb, 1024, 1024);
  ctx_mfma<<<dim3(64, 8), blk, 0, stream>>>(phiK, Vb, ctx, ksum);
  attn_mfma<<<dim3(64, 32), blk, 0, stream>>>(phiQ, ctx, ksum, attn);
  // out projection + residual(src fp32) -> bf16
  gemm256<3><<<dim3(64, 4), blk5, 0, stream>>>(
      attn, Wo_b, bo, nullptr, nullptr, src, nullptr, x1b, nullptr, nullptr, 1024, 1024);
  ln_kernel<<<16384, blk, 0, stream>>>(x1b, g1, be1, out1b, nullptr);
  // FFN
  gemm256<2><<<dim3(64, 8), blk5, 0, stream>>>(
      out1b, W1_b, b1, nullptr, nullptr, nullptr, nullptr, H1, nullptr, nullptr, 2048, 1024);
  gemm256<5><<<dim3(64, 4), blk5, 0, stream>>>(
      H1, W2_b, b2, nullptr, nullptr, nullptr, out1b, x2b, nullptr, nullptr, 1024, 2048);
  ln_kernel<<<16384, blk, 0, stream>>>(x2b, g2, be2, nullptr, outf);
}